// Round 1
// baseline (10126.889 us; speedup 1.0000x reference)
//
#include <hip/hip_runtime.h>

#define NN 10000
#define NE 320000
#define F  128

// ---------- CSR build ----------
__global__ void count_kernel(const int* __restrict__ dst, int* __restrict__ deg) {
    int e = blockIdx.x * 256 + threadIdx.x;
    if (e < NE) atomicAdd(&deg[dst[e]], 1);
}

__global__ __launch_bounds__(1024) void scan_kernel(const int* __restrict__ deg,
                                                    int* __restrict__ offs,
                                                    int* __restrict__ cursor,
                                                    float* __restrict__ invdeg) {
    __shared__ int s[1024];
    int t = threadIdx.x;
    int lo = t * 10;
    int hi = min(lo + 10, NN);
    int sum = 0;
    for (int i = lo; i < hi; ++i) sum += deg[i];
    s[t] = sum;
    __syncthreads();
    // Hillis-Steele inclusive scan over 1024 partials
    for (int off = 1; off < 1024; off <<= 1) {
        int v = (t >= off) ? s[t - off] : 0;
        __syncthreads();
        s[t] += v;
        __syncthreads();
    }
    int base = s[t] - sum;  // exclusive prefix
    for (int i = lo; i < hi; ++i) {
        int c = deg[i];
        offs[i]   = base;
        cursor[i] = base;
        invdeg[i] = 1.0f / (float)c;  // every node has >=1 in-edge
        base += c;
    }
    if (t == 0) offs[NN] = NE;
}

__global__ void fill_kernel(const int* __restrict__ dst, int* __restrict__ cursor,
                            int* __restrict__ csr) {
    int e = blockIdx.x * 256 + threadIdx.x;
    if (e < NE) {
        int p = atomicAdd(&cursor[dst[e]], 1);
        csr[p] = e;
    }
}

// ---------- layer pieces ----------
// step1 (layer 1 only): node_a[n] = mean over in-edges of edge_feats
__global__ void seg_mean_edges(const float* __restrict__ ef, const int* __restrict__ offs,
                               const int* __restrict__ csr, const float* __restrict__ invdeg,
                               float* __restrict__ nodeA) {
    int n = blockIdx.x, f = threadIdx.x;
    int a = offs[n], b = offs[n + 1];
    float acc = 0.f;
    for (int i = a; i < b; ++i) acc += ef[(size_t)csr[i] * F + f];
    nodeA[n * F + f] = acc * invdeg[n];
}

// step1 finish for layers 2..5: node_a (raw scatter sums) *= invdeg
__global__ void normalize_kernel(float* __restrict__ nodeA, const float* __restrict__ invdeg) {
    int i = blockIdx.x * 256 + threadIdx.x;
    if (i < NN * F) nodeA[i] *= invdeg[i >> 7];
}

// step2: node_b[n] = sum over in-edges e of node_a[src[e]]
__global__ void seg_sum_src(const float* __restrict__ nodeA, const int* __restrict__ offs,
                            const int* __restrict__ csr, const int* __restrict__ srcA,
                            float* __restrict__ nodeB) {
    int n = blockIdx.x, f = threadIdx.x;
    int a = offs[n], b = offs[n + 1];
    float acc = 0.f;
    for (int i = a; i < b; ++i) acc += nodeA[srcA[csr[i]] * F + f];
    nodeB[n * F + f] = acc;
}

// steps 3+4 (+ fused next-layer step1 scatter):
// x_e = 0.5*(node_b[src]+node_b[dst]); y = (relu)(W x + b)
// SCATTER: atomicAdd y into node_acc[dst] (raw segment sums for next layer)
// else:    write y to edge output (final layer)
template <int OUT, bool RELU, bool SCATTER>
__global__ __launch_bounds__(256) void gemm_edge(const float* __restrict__ nodeB,
                                                 const float* __restrict__ Wm,
                                                 const float* __restrict__ bias,
                                                 const int* __restrict__ srcA,
                                                 const int* __restrict__ dstA,
                                                 float* __restrict__ outp) {
    __shared__ float Ws[F][OUT + 4];   // W transposed: Ws[k][o] = W[o][k]
    __shared__ float Xs[32][F + 4];
    int tid = threadIdx.x;
    for (int i = tid; i < OUT * F; i += 256) {
        int o = i >> 7, k = i & 127;   // global coalesced read of W[o][k]
        Ws[k][o] = Wm[i];
    }
    int e0 = blockIdx.x * 32;
    for (int i = tid; i < 32 * F; i += 256) {
        int el = i >> 7, f = i & 127;
        int e = e0 + el;
        Xs[el][f] = 0.5f * (nodeB[srcA[e] * F + f] + nodeB[dstA[e] * F + f]);
    }
    __syncthreads();

    const int r = tid >> 3;          // edge row within tile (0..31)
    const int og = tid & 7;          // output group
    constexpr int NO = OUT / 8;      // 16 (hidden) or 8 (final)
    const int o0 = og * NO;
    float acc[NO];
#pragma unroll
    for (int j = 0; j < NO; ++j) acc[j] = 0.f;

#pragma unroll 4
    for (int k = 0; k < F; ++k) {
        float xv = Xs[r][k];
        const float4* wrow = reinterpret_cast<const float4*>(&Ws[k][o0]);
#pragma unroll
        for (int j4 = 0; j4 < NO / 4; ++j4) {
            float4 w = wrow[j4];
            acc[j4 * 4 + 0] += xv * w.x;
            acc[j4 * 4 + 1] += xv * w.y;
            acc[j4 * 4 + 2] += xv * w.z;
            acc[j4 * 4 + 3] += xv * w.w;
        }
    }

    int e = e0 + r;
    int d = dstA[e];
#pragma unroll
    for (int j = 0; j < NO; ++j) {
        float y = acc[j] + bias[o0 + j];
        if (RELU) y = fmaxf(y, 0.f);
        if (SCATTER) atomicAdd(&outp[d * F + o0 + j], y);
        else         outp[(size_t)e * OUT + o0 + j] = y;
    }
}

extern "C" void kernel_launch(void* const* d_in, const int* in_sizes, int n_in,
                              void* d_out, int out_size, void* d_ws, size_t ws_size,
                              hipStream_t stream) {
    const float* ef  = (const float*)d_in[0];
    const int*   src = (const int*)d_in[1];
    const int*   dst = (const int*)d_in[2];
    const float* W1 = (const float*)d_in[3];  const float* b1 = (const float*)d_in[4];
    const float* W2 = (const float*)d_in[5];  const float* b2 = (const float*)d_in[6];
    const float* W3 = (const float*)d_in[7];  const float* b3 = (const float*)d_in[8];
    const float* W4 = (const float*)d_in[9];  const float* b4 = (const float*)d_in[10];
    const float* W5 = (const float*)d_in[11]; const float* b5 = (const float*)d_in[12];
    float* out = (float*)d_out;

    char* p = (char*)d_ws;
    auto alloc = [&](size_t bytes) {
        char* r = p;
        p += (bytes + 255) & ~(size_t)255;
        return r;
    };
    int*   deg    = (int*)alloc(NN * 4);
    int*   offs   = (int*)alloc((NN + 1) * 4);
    int*   cursor = (int*)alloc(NN * 4);
    int*   csr    = (int*)alloc((size_t)NE * 4);
    float* invdeg = (float*)alloc(NN * 4);
    float* nodeA  = (float*)alloc((size_t)NN * F * 4);
    float* nodeB  = (float*)alloc((size_t)NN * F * 4);

    // CSR build (rebuilt every call; deterministic work)
    hipMemsetAsync(deg, 0, NN * 4, stream);
    count_kernel<<<(NE + 255) / 256, 256, 0, stream>>>(dst, deg);
    scan_kernel<<<1, 1024, 0, stream>>>(deg, offs, cursor, invdeg);
    fill_kernel<<<(NE + 255) / 256, 256, 0, stream>>>(dst, cursor, csr);

    // ---- layer 1 ----
    seg_mean_edges<<<NN, 128, 0, stream>>>(ef, offs, csr, invdeg, nodeA);
    seg_sum_src<<<NN, 128, 0, stream>>>(nodeA, offs, csr, src, nodeB);
    hipMemsetAsync(nodeA, 0, (size_t)NN * F * 4, stream);
    gemm_edge<128, true, true><<<NE / 32, 256, 0, stream>>>(nodeB, W1, b1, src, dst, nodeA);

    // ---- layers 2..4 ----
    const float* Wl[3] = {W2, W3, W4};
    const float* bl[3] = {b2, b3, b4};
    for (int L = 0; L < 3; ++L) {
        normalize_kernel<<<(NN * F + 255) / 256, 256, 0, stream>>>(nodeA, invdeg);
        seg_sum_src<<<NN, 128, 0, stream>>>(nodeA, offs, csr, src, nodeB);
        hipMemsetAsync(nodeA, 0, (size_t)NN * F * 4, stream);
        gemm_edge<128, true, true><<<NE / 32, 256, 0, stream>>>(nodeB, Wl[L], bl[L], src, dst, nodeA);
    }

    // ---- layer 5 (no relu, write edge outputs) ----
    normalize_kernel<<<(NN * F + 255) / 256, 256, 0, stream>>>(nodeA, invdeg);
    seg_sum_src<<<NN, 128, 0, stream>>>(nodeA, offs, csr, src, nodeB);
    gemm_edge<64, false, false><<<NE / 32, 256, 0, stream>>>(nodeB, W5, b5, src, dst, out);
}

// Round 2
// 464.642 us; speedup vs baseline: 21.7951x; 21.7951x over previous
//
#include <hip/hip_runtime.h>

#define NN 10000
#define NN_P 10048          // padded rows for guard-free GEMM loads
#define NE 320000
#define F  128

// ---------- CSR build ----------
__global__ void count_kernel(const int* __restrict__ dst, int* __restrict__ deg) {
    int e = blockIdx.x * 256 + threadIdx.x;
    if (e < NE) atomicAdd(&deg[dst[e]], 1);
}

__global__ __launch_bounds__(1024) void scan_kernel(const int* __restrict__ deg,
                                                    int* __restrict__ offs,
                                                    int* __restrict__ cursor,
                                                    float* __restrict__ invdeg) {
    __shared__ int s[1024];
    int t = threadIdx.x;
    int lo = t * 10;
    int hi = min(lo + 10, NN);
    int sum = 0;
    for (int i = lo; i < hi; ++i) sum += deg[i];
    s[t] = sum;
    __syncthreads();
    for (int off = 1; off < 1024; off <<= 1) {
        int v = (t >= off) ? s[t - off] : 0;
        __syncthreads();
        s[t] += v;
        __syncthreads();
    }
    int base = s[t] - sum;  // exclusive prefix
    for (int i = lo; i < hi; ++i) {
        int c = deg[i];
        offs[i]   = base;
        cursor[i] = base;
        invdeg[i] = 1.0f / (float)c;
        base += c;
    }
    if (t == 0) offs[NN] = NE;
}

__global__ void fill_kernel(const int* __restrict__ dst, int* __restrict__ cursor,
                            int* __restrict__ csr) {
    int e = blockIdx.x * 256 + threadIdx.x;
    if (e < NE) {
        int p = atomicAdd(&cursor[dst[e]], 1);
        csr[p] = e;
    }
}

// csrc[i] = src[csr[i]] : pre-resolve the double indirection used by every layer
__global__ void build_csrc(const int* __restrict__ csr, const int* __restrict__ src,
                           int* __restrict__ csrc) {
    int i = blockIdx.x * 256 + threadIdx.x;
    if (i < NE) csrc[i] = src[csr[i]];
}

// ---------- layer pieces ----------
// layer 1 step 1: nodeA[n] = mean over in-edges of edge_feats rows (164 MB HBM read)
__global__ void seg_mean_edges(const float* __restrict__ ef, const int* __restrict__ offs,
                               const int* __restrict__ csr, const float* __restrict__ invdeg,
                               float* __restrict__ nodeA) {
    int n = blockIdx.x, f = threadIdx.x;
    int a = offs[n], bnd = offs[n + 1];
    float acc = 0.f;
    int i = a;
    for (; i + 3 < bnd; i += 4) {
        int e0 = csr[i], e1 = csr[i + 1], e2 = csr[i + 2], e3 = csr[i + 3];
        acc += ef[(size_t)e0 * F + f] + ef[(size_t)e1 * F + f]
             + ef[(size_t)e2 * F + f] + ef[(size_t)e3 * F + f];
    }
    for (; i < bnd; ++i) acc += ef[(size_t)csr[i] * F + f];
    nodeA[n * F + f] = acc * invdeg[n];
}

// layers 2..5 step 1 fused with previous layer's edge compute:
// nodeA[n] = invdeg[n] * sum_{e in(n)} relu(0.5*(z[src_e]+z[n]) + b_prev)
__global__ void edge_agg(const float* __restrict__ z, const float* __restrict__ bias,
                         const int* __restrict__ offs, const int* __restrict__ csrc,
                         const float* __restrict__ invdeg, float* __restrict__ nodeA) {
    int n = blockIdx.x, f = threadIdx.x;
    int a = offs[n], bnd = offs[n + 1];
    float zn = z[n * F + f];
    float bf = bias[f];
    float acc = 0.f;
    int i = a;
    for (; i + 3 < bnd; i += 4) {
        int s0 = csrc[i], s1 = csrc[i + 1], s2 = csrc[i + 2], s3 = csrc[i + 3];
        acc += fmaxf(0.5f * (z[s0 * F + f] + zn) + bf, 0.f)
             + fmaxf(0.5f * (z[s1 * F + f] + zn) + bf, 0.f)
             + fmaxf(0.5f * (z[s2 * F + f] + zn) + bf, 0.f)
             + fmaxf(0.5f * (z[s3 * F + f] + zn) + bf, 0.f);
    }
    for (; i < bnd; ++i)
        acc += fmaxf(0.5f * (z[csrc[i] * F + f] + zn) + bf, 0.f);
    nodeA[n * F + f] = acc * invdeg[n];
}

// step 2: nodeB[n] = sum over in-edges of nodeA[src]
__global__ void seg_sum(const float* __restrict__ nodeA, const int* __restrict__ offs,
                        const int* __restrict__ csrc, float* __restrict__ nodeB) {
    int n = blockIdx.x, f = threadIdx.x;
    int a = offs[n], bnd = offs[n + 1];
    float acc = 0.f;
    int i = a;
    for (; i + 3 < bnd; i += 4) {
        int s0 = csrc[i], s1 = csrc[i + 1], s2 = csrc[i + 2], s3 = csrc[i + 3];
        acc += nodeA[s0 * F + f] + nodeA[s1 * F + f]
             + nodeA[s2 * F + f] + nodeA[s3 * F + f];
    }
    for (; i < bnd; ++i) acc += nodeA[csrc[i] * F + f];
    nodeB[n * F + f] = acc;
}

// node-level GEMM: Z[NN x OUT] = X[NN x 128] @ W[OUT x 128]^T  (no bias)
// grid (OUT/64, ceil(NN/64)), block (16,16); each thread a 4x4 micro-tile
template <int OUT>
__global__ __launch_bounds__(256) void node_gemm(const float* __restrict__ X,
                                                 const float* __restrict__ Wm,
                                                 float* __restrict__ Z) {
    int c0 = blockIdx.x * 64 + threadIdx.x * 4;
    int r0 = blockIdx.y * 64 + threadIdx.y * 4;   // < NN_P (X is padded)
    float acc[4][4] = {};
#pragma unroll 8
    for (int k = 0; k < 128; k += 4) {
        float4 xv[4], wv[4];
#pragma unroll
        for (int i = 0; i < 4; ++i)
            xv[i] = *reinterpret_cast<const float4*>(&X[(r0 + i) * F + k]);
#pragma unroll
        for (int j = 0; j < 4; ++j)
            wv[j] = *reinterpret_cast<const float4*>(&Wm[(c0 + j) * F + k]);
#pragma unroll
        for (int i = 0; i < 4; ++i)
#pragma unroll
            for (int j = 0; j < 4; ++j)
                acc[i][j] += xv[i].x * wv[j].x + xv[i].y * wv[j].y
                           + xv[i].z * wv[j].z + xv[i].w * wv[j].w;
    }
#pragma unroll
    for (int i = 0; i < 4; ++i) {
        if (r0 + i < NN) {
#pragma unroll
            for (int j = 0; j < 4; ++j) Z[(r0 + i) * OUT + c0 + j] = acc[i][j];
        }
    }
}

// final: out[e] = 0.5*(z5[src]+z5[dst]) + b5   (64 feats per edge, one wave-half each)
__global__ void edge_out(const float* __restrict__ z5, const float* __restrict__ b5v,
                         const int* __restrict__ src, const int* __restrict__ dst,
                         float* __restrict__ outp) {
    int e = blockIdx.x * 4 + (threadIdx.x >> 6);
    int f = threadIdx.x & 63;
    if (e < NE)
        outp[(size_t)e * 64 + f] =
            0.5f * (z5[src[e] * 64 + f] + z5[dst[e] * 64 + f]) + b5v[f];
}

extern "C" void kernel_launch(void* const* d_in, const int* in_sizes, int n_in,
                              void* d_out, int out_size, void* d_ws, size_t ws_size,
                              hipStream_t stream) {
    const float* ef  = (const float*)d_in[0];
    const int*   src = (const int*)d_in[1];
    const int*   dst = (const int*)d_in[2];
    const float* W1 = (const float*)d_in[3];  const float* b1 = (const float*)d_in[4];
    const float* W2 = (const float*)d_in[5];  const float* b2 = (const float*)d_in[6];
    const float* W3 = (const float*)d_in[7];  const float* b3 = (const float*)d_in[8];
    const float* W4 = (const float*)d_in[9];  const float* b4 = (const float*)d_in[10];
    const float* W5 = (const float*)d_in[11]; const float* b5 = (const float*)d_in[12];
    float* out = (float*)d_out;

    char* p = (char*)d_ws;
    auto alloc = [&](size_t bytes) {
        char* r = p;
        p += (bytes + 255) & ~(size_t)255;
        return r;
    };
    int*   deg    = (int*)alloc(NN * 4);
    int*   offs   = (int*)alloc((NN + 1) * 4);
    int*   cursor = (int*)alloc(NN * 4);
    int*   csr    = (int*)alloc((size_t)NE * 4);
    int*   csrc   = (int*)alloc((size_t)NE * 4);
    float* invdeg = (float*)alloc(NN * 4);
    float* nodeA  = (float*)alloc((size_t)NN_P * F * 4);
    float* nodeB  = (float*)alloc((size_t)NN_P * F * 4);
    float* z      = (float*)alloc((size_t)NN_P * F * 4);

    // CSR build
    hipMemsetAsync(deg, 0, NN * 4, stream);
    count_kernel<<<(NE + 255) / 256, 256, 0, stream>>>(dst, deg);
    scan_kernel<<<1, 1024, 0, stream>>>(deg, offs, cursor, invdeg);
    fill_kernel<<<(NE + 255) / 256, 256, 0, stream>>>(dst, cursor, csr);
    build_csrc<<<(NE + 255) / 256, 256, 0, stream>>>(csr, src, csrc);

    dim3 blk(16, 16);
    dim3 grid128(2, (NN + 63) / 64);
    dim3 grid64(1, (NN + 63) / 64);

    // ---- layer 1 ----
    seg_mean_edges<<<NN, 128, 0, stream>>>(ef, offs, csr, invdeg, nodeA);
    seg_sum<<<NN, 128, 0, stream>>>(nodeA, offs, csrc, nodeB);
    node_gemm<128><<<grid128, blk, 0, stream>>>(nodeB, W1, z);

    // ---- layers 2..4: edge_agg uses previous layer's (z, b) ----
    const float* bprev[3] = {b1, b2, b3};
    const float* Wl[3]    = {W2, W3, W4};
    for (int L = 0; L < 3; ++L) {
        edge_agg<<<NN, 128, 0, stream>>>(z, bprev[L], offs, csrc, invdeg, nodeA);
        seg_sum<<<NN, 128, 0, stream>>>(nodeA, offs, csrc, nodeB);
        node_gemm<128><<<grid128, blk, 0, stream>>>(nodeB, Wl[L], z);
    }

    // ---- layer 5 ----
    edge_agg<<<NN, 128, 0, stream>>>(z, b4, offs, csrc, invdeg, nodeA);
    seg_sum<<<NN, 128, 0, stream>>>(nodeA, offs, csrc, nodeB);
    node_gemm<64><<<grid64, blk, 0, stream>>>(nodeB, W5, z);

    // ---- final per-edge output (82 MB write) ----
    edge_out<<<(NE + 3) / 4, 256, 0, stream>>>(z, b5, src, dst, out);
}